// Round 5
// baseline (393.003 us; speedup 1.0000x reference)
//
#include <hip/hip_runtime.h>
#include <math.h>

#define SEQLEN 2048
#define DIN 2048
#define NH 32
#define NKV 8
#define HD 64
#define DQ (NH*HD)    // 2048
#define DKV (NKV*HD)  // 512

using u16 = unsigned short;
using u32 = unsigned int;
using bf16x8 = __attribute__((ext_vector_type(8))) __bf16;
using f32x4  = __attribute__((ext_vector_type(4))) float;

__device__ __forceinline__ u16 f2b(float f) {
    union { float f; u32 u; } x; x.f = f;
    u32 u = x.u;
    u32 r = (u + 0x7fffu + ((u >> 16) & 1u)) >> 16;   // RNE
    return (u16)r;
}
__device__ __forceinline__ float b2f(u16 b) {
    union { u32 u; float f; } x; x.u = ((u32)b) << 16;
    return x.f;
}

// async global->LDS, 16B/lane; lds base wave-uniform, lane writes at lane*16B.
__device__ __forceinline__ void gl2lds16(const u16* g, u16* l) {
    __builtin_amdgcn_global_load_lds(
        (const __attribute__((address_space(1))) void*)g,
        (__attribute__((address_space(3))) void*)l,
        16, 0, 0);
}

// Swizzled chunk staging: a chunk is 8 rows x 64 k (u16), 1 KB.
// lane -> (row = lane&7, k-octet = lane>>3). LDS elem (row,kk) lives at
// chunk*512 + (kk>>3)*64 + (row&7)*8 + (kk&7). b128 frag reads then cover
// all 32 banks (2-way alias only = free).
__device__ __forceinline__ int lds_off(int row, int kk0) {
    return (row >> 3) * 512 + (kk0 >> 3) * 64 + (row & 7) * 8;
}

// ---------------------------------------------------------------------------
// Fused prep: cast x -> bf16, transpose-cast wq/wk/wv (into contiguous QKV
// weight [3072][2048]) and wo. One launch, block-ranged routing.
// ---------------------------------------------------------------------------
__global__ __launch_bounds__(256) void prep(const float* __restrict__ x,
                                            const float* __restrict__ wq,
                                            const float* __restrict__ wk,
                                            const float* __restrict__ wv,
                                            const float* __restrict__ wo,
                                            u16* __restrict__ xb,
                                            u16* __restrict__ wqkvT,
                                            u16* __restrict__ woT) {
    const int b = blockIdx.x;
    const int t = threadIdx.x;
    if (b < 4096) {                       // x cast: 4096 * 1024 elems
        int i = b * 1024 + t * 4;
        float4 v = *reinterpret_cast<const float4*>(&x[i]);
        ushort4 o;
        o.x = f2b(v.x); o.y = f2b(v.y); o.z = f2b(v.z); o.w = f2b(v.w);
        *reinterpret_cast<ushort4*>(&xb[i]) = o;
        return;
    }
    __shared__ float tile[32][33];
    int b2 = b - 4096;
    const float* src; u16* dst; int C, bx, by;
    if (b2 < 4096)      { src = wq; dst = wqkvT;                       C = 2048; bx = b2 & 63; by = b2 >> 6; }
    else if (b2 < 5120) { b2 -= 4096; src = wk; dst = wqkvT + (size_t)2048 * 2048; C = 512; bx = b2 & 15; by = b2 >> 4; }
    else if (b2 < 6144) { b2 -= 5120; src = wv; dst = wqkvT + (size_t)2560 * 2048; C = 512; bx = b2 & 15; by = b2 >> 4; }
    else                { b2 -= 6144; src = wo; dst = woT;             C = 2048; bx = b2 & 63; by = b2 >> 6; }
    const int R = 2048;
    const int c0 = bx * 32, r0 = by * 32;
    const int tr = t >> 5, tc = t & 31;
    #pragma unroll
    for (int i = 0; i < 4; ++i)
        tile[tr + i * 8][tc] = src[(size_t)(r0 + tr + i * 8) * C + c0 + tc];
    __syncthreads();
    #pragma unroll
    for (int i = 0; i < 4; ++i)
        dst[(size_t)(c0 + tr + i * 8) * R + r0 + tc] = f2b(tile[tc][tr + i * 8]);
}

// ---------------------------------------------------------------------------
// zero fp32 region (attnF + Lbuf), n multiple of 1024
// ---------------------------------------------------------------------------
__global__ __launch_bounds__(256) void zero_f32(float* __restrict__ p) {
    int i = blockIdx.x * 1024 + threadIdx.x * 4;
    *reinterpret_cast<float4*>(&p[i]) = make_float4(0.f, 0.f, 0.f, 0.f);
}

// ---------------------------------------------------------------------------
// bf16 MFMA GEMM: BM=128, BN=64, BK=64, glds swizzled staging, 256 thr.
// A[M][K], Bt[N][K] bf16. MODE 0: fp32 C. MODE 1: QKV routing epilogue.
// ---------------------------------------------------------------------------
template<int MODE>
__global__ __launch_bounds__(256) void gemm_glds(const u16* __restrict__ A,
                                                 const u16* __restrict__ Bt,
                                                 float* __restrict__ Cf,
                                                 u16* __restrict__ Qb,
                                                 u16* __restrict__ Kb,
                                                 u16* __restrict__ VtG,
                                                 int M, int N, int K) {
    __shared__ u16 As[128 * 64];   // 16 chunks
    __shared__ u16 Bs[64 * 64];    //  8 chunks
    const int t = threadIdx.x;
    const int w = t >> 6, lane = t & 63, quad = lane >> 4, l15 = lane & 15;
    const int m0 = blockIdx.y * 128, n0 = blockIdx.x * 64;
    const int wr = (w >> 1) * 64, wc = (w & 1) * 32;
    const int srow = lane & 7, soct = (lane >> 3) * 8;

    f32x4 acc[4][2];
    #pragma unroll
    for (int mt = 0; mt < 4; ++mt)
        #pragma unroll
        for (int nt = 0; nt < 2; ++nt)
            #pragma unroll
            for (int r = 0; r < 4; ++r) acc[mt][nt][r] = 0.0f;

    for (int k0 = 0; k0 < K; k0 += 64) {
        __syncthreads();
        #pragma unroll
        for (int i = 0; i < 4; ++i) {
            int c = w * 4 + i;   // A chunk 0..15 (rows c*8..c*8+7)
            gl2lds16(A + (size_t)(m0 + c * 8 + srow) * K + k0 + soct, As + c * 512);
        }
        #pragma unroll
        for (int i = 0; i < 2; ++i) {
            int c = w * 2 + i;   // B chunk 0..7
            gl2lds16(Bt + (size_t)(n0 + c * 8 + srow) * K + k0 + soct, Bs + c * 512);
        }
        __syncthreads();

        #pragma unroll
        for (int ks = 0; ks < 2; ++ks) {
            const int kk0 = ks * 32 + quad * 8;
            bf16x8 a[4], b[2];
            #pragma unroll
            for (int mt = 0; mt < 4; ++mt)
                a[mt] = *reinterpret_cast<const bf16x8*>(&As[lds_off(wr + mt * 16 + l15, kk0)]);
            #pragma unroll
            for (int nt = 0; nt < 2; ++nt)
                b[nt] = *reinterpret_cast<const bf16x8*>(&Bs[lds_off(wc + nt * 16 + l15, kk0)]);
            #pragma unroll
            for (int mt = 0; mt < 4; ++mt)
                #pragma unroll
                for (int nt = 0; nt < 2; ++nt)
                    acc[mt][nt] = __builtin_amdgcn_mfma_f32_16x16x32_bf16(a[mt], b[nt], acc[mt][nt], 0, 0, 0);
        }
    }

    #pragma unroll
    for (int mt = 0; mt < 4; ++mt)
        #pragma unroll
        for (int nt = 0; nt < 2; ++nt) {
            const int rb  = m0 + wr + mt * 16 + quad * 4;
            const int col = n0 + wc + nt * 16 + l15;
            if (MODE == 0) {
                #pragma unroll
                for (int r = 0; r < 4; ++r)
                    Cf[(size_t)(rb + r) * N + col] = acc[mt][nt][r];
            } else if (col >= 2560) {      // V: store transposed, packed
                ushort4 o;
                o.x = f2b(acc[mt][nt][0]); o.y = f2b(acc[mt][nt][1]);
                o.z = f2b(acc[mt][nt][2]); o.w = f2b(acc[mt][nt][3]);
                *reinterpret_cast<ushort4*>(&VtG[(size_t)(col - 2560) * 2048 + rb]) = o;
            } else if (col >= 2048) {      // K
                #pragma unroll
                for (int r = 0; r < 4; ++r)
                    Kb[(size_t)(rb + r) * 512 + (col - 2048)] = f2b(acc[mt][nt][r]);
            } else {                        // Q
                #pragma unroll
                for (int r = 0; r < 4; ++r)
                    Qb[(size_t)(rb + r) * 2048 + col] = f2b(acc[mt][nt][r]);
            }
        }
}

// ---------------------------------------------------------------------------
// In-place RMSNorm + RoPE on bf16 Q (pre-scaled by 0.125*log2e) and K.
// ---------------------------------------------------------------------------
__global__ __launch_bounds__(256) void norm_rope_bf16(u16* __restrict__ Qb,
                                                      u16* __restrict__ Kb,
                                                      const float* __restrict__ cosb,
                                                      const float* __restrict__ sinb,
                                                      const float* __restrict__ qw,
                                                      const float* __restrict__ kw) {
    const int s    = blockIdx.x;
    const int wave = threadIdx.x >> 6;
    const int lane = threadIdx.x & 63;
    const int head = blockIdx.y * 4 + wave;   // 0..39

    u16* base;
    const float* w;
    if (head < NH) { base = Qb + (size_t)s * DQ + head * HD;         w = qw; }
    else           { base = Kb + (size_t)s * DKV + (head - NH) * HD; w = kw; }

    float v  = b2f(base[lane]);
    float ss = v * v;
    #pragma unroll
    for (int off = 32; off; off >>= 1) ss += __shfl_xor(ss, off);
    float r  = rsqrtf(ss * (1.0f / 64.0f) + 1e-6f);
    float vn = v * r * w[lane];

    float partner = __shfl_xor(vn, 32);
    float sgn = (lane < 32) ? -1.0f : 1.0f;
    float res = vn * cosb[s * HD + lane] + sgn * partner * sinb[s * HD + lane];
    if (head < NH) res *= 0.18033688f;   // 0.125 * log2(e)
    base[lane] = f2b(res);
}

// ---------------------------------------------------------------------------
// Chunked MFMA flash attention. Fixed-shift softmax (p=exp2(s-24)) makes
// (O,l) partials over disjoint KV ranges ADDITIVE -> flash-decode split with
// plain fp32 atomicAdd combine, no per-chunk max bookkeeping.
// grid 4096: h=b&31, qt=(b>>5)&31, chunk=b>>10 (8 KV-tiles per chunk).
// Inactive chunks exit. S^T=K.Q^T; O^T += V^T.P^T (virtual-K remap).
// ---------------------------------------------------------------------------
__global__ __launch_bounds__(256) void attn_chunk(const u16* __restrict__ Qb,
                                                  const u16* __restrict__ Kb,
                                                  const u16* __restrict__ VtG,
                                                  float* __restrict__ attnF,
                                                  float* __restrict__ Lbuf) {
    const int b  = blockIdx.x;
    const int h  = b & 31;
    const int qt = (b >> 5) & 31;
    const int ch = b >> 10;
    if (ch * 8 > qt) return;
    const int q0  = qt * 64;
    const int kvh = h >> 2;
    const int kt_beg = ch * 8;
    const int kt_end = min(kt_beg + 8, qt + 1);

    __shared__ u16 Ks[64 * 64];   // [kv][d], swizzled chunks
    __shared__ u16 Vt[64 * 64];   // [d][kv], swizzled chunks

    const int t = threadIdx.x;
    const int w = t >> 6, lane = t & 63, quad = lane >> 4, l15 = lane & 15;
    const int srow = lane & 7, soct = (lane >> 3) * 8;

    // Q B-frags from global: q = q0 + w*16 + l15 (already exp2-scaled).
    const u16* qrow = Qb + (size_t)(q0 + w * 16 + l15) * DQ + h * HD;
    bf16x8 qB[2];
    qB[0] = *reinterpret_cast<const bf16x8*>(qrow + quad * 8);
    qB[1] = *reinterpret_cast<const bf16x8*>(qrow + 32 + quad * 8);

    f32x4 o[4];
    #pragma unroll
    for (int dt = 0; dt < 4; ++dt)
        #pragma unroll
        for (int r = 0; r < 4; ++r) o[dt][r] = 0.0f;
    float lpart = 0.0f;

    for (int kt = kt_beg; kt < kt_end; ++kt) {
        const int k0 = kt * 64;
        __syncthreads();
        #pragma unroll
        for (int i = 0; i < 2; ++i) {
            int c = w * 2 + i;   // 0..7
            gl2lds16(Kb  + (size_t)(k0 + c * 8 + srow) * DKV + kvh * HD + soct, Ks + c * 512);
            gl2lds16(VtG + (size_t)(kvh * HD + c * 8 + srow) * 2048 + k0 + soct, Vt + c * 512);
        }
        __syncthreads();

        // S^T = K.Q^T
        f32x4 s[4];
        #pragma unroll
        for (int kt4 = 0; kt4 < 4; ++kt4)
            #pragma unroll
            for (int r = 0; r < 4; ++r) s[kt4][r] = 0.0f;
        #pragma unroll
        for (int ks = 0; ks < 2; ++ks) {
            const int kk0 = ks * 32 + quad * 8;
            #pragma unroll
            for (int kt4 = 0; kt4 < 4; ++kt4) {
                bf16x8 ka = *reinterpret_cast<const bf16x8*>(&Ks[lds_off(kt4 * 16 + l15, kk0)]);
                s[kt4] = __builtin_amdgcn_mfma_f32_16x16x32_bf16(ka, qB[ks], s[kt4], 0, 0, 0);
            }
        }

        const bool diag = (kt == qt);
        u32 pb[4][2];
        #pragma unroll
        for (int kt4 = 0; kt4 < 4; ++kt4) {
            float p[4];
            #pragma unroll
            for (int r = 0; r < 4; ++r) {
                float sv = s[kt4][r];
                if (diag && (kt4 * 16 + quad * 4 + r) > (w * 16 + l15)) sv = -1e30f;
                p[r] = exp2f(sv - 24.0f);
                lpart += p[r];
            }
            pb[kt4][0] = ((u32)f2b(p[1]) << 16) | f2b(p[0]);
            pb[kt4][1] = ((u32)f2b(p[3]) << 16) | f2b(p[2]);
        }

        // O^T += V^T.P^T (zero-padded virtual K)
        // V A-frag slot (quad, j<4) must hold V^T[d = dt*16+l15][kv = kt4*16+quad*4+j].
        #pragma unroll
        for (int kt4 = 0; kt4 < 4; ++kt4) {
            union { bf16x8 v; u32 u[4]; } pu;
            pu.u[0] = pb[kt4][0]; pu.u[1] = pb[kt4][1]; pu.u[2] = 0; pu.u[3] = 0;
            const int kvc = kt4 * 16 + quad * 4;          // kv column base
            const int kvoct = kvc >> 3;                   // = kt4*2 + (quad>>1)
            const int kvrem = kvc & 7;                    // = (quad&1)*4
            #pragma unroll
            for (int dt = 0; dt < 4; ++dt) {
                union { bf16x8 v; u32 u[4]; } va;
                const int row = dt * 16 + l15;
                uint2 vv = *reinterpret_cast<const uint2*>(
                    &Vt[(row >> 3) * 512 + kvoct * 64 + (row & 7) * 8 + kvrem]);
                va.u[0] = vv.x; va.u[1] = vv.y; va.u[2] = 0; va.u[3] = 0;
                o[dt] = __builtin_amdgcn_mfma_f32_16x16x32_bf16(va.v, pu.v, o[dt], 0, 0, 0);
            }
        }
    }

    // additive combine
    lpart += __shfl_xor(lpart, 16);
    lpart += __shfl_xor(lpart, 32);
    if (quad == 0)
        atomicAdd(&Lbuf[h * 2048 + q0 + w * 16 + l15], lpart);
    float* ob = attnF + (size_t)(q0 + w * 16 + l15) * 2048 + h * 64;
    #pragma unroll
    for (int dt = 0; dt < 4; ++dt)
        #pragma unroll
        for (int r = 0; r < 4; ++r)
            atomicAdd(&ob[dt * 16 + quad * 4 + r], o[dt][r]);
}

// ---------------------------------------------------------------------------
// normalize (1/l) + cast fp32 -> bf16
// ---------------------------------------------------------------------------
__global__ __launch_bounds__(256) void norm_cast(const float* __restrict__ attnF,
                                                 const float* __restrict__ Lbuf,
                                                 u16* __restrict__ attnb) {
    int i = blockIdx.x * 1024 + threadIdx.x * 4;
    int q = i >> 11, f = i & 2047, h = f >> 6;
    float inv = 1.0f / Lbuf[h * 2048 + q];
    float4 v = *reinterpret_cast<const float4*>(&attnF[i]);
    ushort4 o;
    o.x = f2b(v.x * inv); o.y = f2b(v.y * inv);
    o.z = f2b(v.z * inv); o.w = f2b(v.w * inv);
    *reinterpret_cast<ushort4*>(&attnb[i]) = o;
}

// ---------------------------------------------------------------------------
extern "C" void kernel_launch(void* const* d_in, const int* in_sizes, int n_in,
                              void* d_out, int out_size, void* d_ws, size_t ws_size,
                              hipStream_t stream) {
    const float* x    = (const float*)d_in[0];
    const float* cosb = (const float*)d_in[1];
    const float* sinb = (const float*)d_in[2];
    const float* wq   = (const float*)d_in[3];
    const float* wk   = (const float*)d_in[4];
    const float* wv   = (const float*)d_in[5];
    const float* wo   = (const float*)d_in[6];
    const float* qnw  = (const float*)d_in[7];
    const float* knw  = (const float*)d_in[8];
    float* out = (float*)d_out;

    char* ws = (char*)d_ws;
    const size_t MB = 1024 * 1024;
    u16*   xb    = (u16*)(ws + 0);          // 8 MB   (dead after QKV gemm)
    u16*   wqkvT = (u16*)(ws + 8  * MB);    // 12 MB  (dead after QKV gemm)
    float* attnF = (float*)(ws + 0);        // 16 MB  (aliases xb+wqkvT)
    float* Lbuf  = (float*)(ws + 16 * MB);  // 256 KB (aliases wqkvT tail)
    u16*   woT   = (u16*)(ws + 20 * MB);    // 8 MB
    u16*   Qb    = (u16*)(ws + 28 * MB);    // 8 MB
    u16*   Kb    = (u16*)(ws + 36 * MB);    // 2 MB
    u16*   VtG   = (u16*)(ws + 38 * MB);    // 2 MB  [512][2048]
    u16*   attnb = (u16*)(ws + 40 * MB);    // 8 MB

    // 1) fused prep: cast x + 4 weight transposes
    prep<<<14336, 256, 0, stream>>>(x, wq, wk, wv, wo, xb, wqkvT, woT);

    // 2) fused QKV projection (V transposed in epilogue)
    gemm_glds<1><<<dim3(3072 / 64, SEQLEN / 128), 256, 0, stream>>>(
        xb, wqkvT, nullptr, Qb, Kb, VtG, SEQLEN, 3072, DIN);

    // 3) zero attnF + Lbuf (xb/wqkvT dead now)
    zero_f32<<<(16 * MB / 4 + 65536) / 1024, 256, 0, stream>>>(attnF);

    // 4) RMSNorm + RoPE (Q into exp2 domain)
    norm_rope_bf16<<<dim3(SEQLEN, 10), 256, 0, stream>>>(Qb, Kb, cosb, sinb, qnw, knw);

    // 5) chunked flash attention, additive partials
    attn_chunk<<<4096, 256, 0, stream>>>(Qb, Kb, VtG, attnF, Lbuf);

    // 6) normalize + cast
    norm_cast<<<4096, 256, 0, stream>>>(attnF, Lbuf, attnb);

    // 7) output projection
    gemm_glds<0><<<dim3(DIN / 64, SEQLEN / 128), 256, 0, stream>>>(
        attnb, woT, out, nullptr, nullptr, nullptr, SEQLEN, DIN, DQ);
}

// Round 6
// 308.478 us; speedup vs baseline: 1.2740x; 1.2740x over previous
//
#include <hip/hip_runtime.h>
#include <math.h>

#define SEQLEN 2048
#define DIN 2048
#define NH 32
#define NKV 8
#define HD 64
#define DQ (NH*HD)    // 2048
#define DKV (NKV*HD)  // 512

using u16 = unsigned short;
using u32 = unsigned int;
using bf16x8 = __attribute__((ext_vector_type(8))) __bf16;
using f32x4  = __attribute__((ext_vector_type(4))) float;

__device__ __forceinline__ u16 f2b(float f) {
    union { float f; u32 u; } x; x.f = f;
    u32 u = x.u;
    u32 r = (u + 0x7fffu + ((u >> 16) & 1u)) >> 16;   // RNE
    return (u16)r;
}

// async global->LDS, 16B/lane; lds base wave-uniform, lane writes at lane*16B.
__device__ __forceinline__ void gl2lds16(const u16* g, u16* l) {
    __builtin_amdgcn_global_load_lds(
        (const __attribute__((address_space(1))) void*)g,
        (__attribute__((address_space(3))) void*)l,
        16, 0, 0);
}

// Swizzled chunk staging: chunk = 8 rows x 64 k (u16), 1 KB.
// Loading lane -> (row = lane&7, k-octet = lane>>3). Elem (row,kk) at
// chunk*512 + (kk>>3)*64 + (row&7)*8 + (kk&7). b128 frag reads cover all
// 32 banks (2-way alias only = free).
__device__ __forceinline__ int lds_off(int row, int kk0) {
    return (row >> 3) * 512 + (kk0 >> 3) * 64 + (row & 7) * 8;
}

// ---------------------------------------------------------------------------
// Fused prep: cast x -> bf16; transpose-cast wq/wk/wv (contiguous [3072][2048])
// and wo.
// ---------------------------------------------------------------------------
__global__ __launch_bounds__(256) void prep(const float* __restrict__ x,
                                            const float* __restrict__ wq,
                                            const float* __restrict__ wk,
                                            const float* __restrict__ wv,
                                            const float* __restrict__ wo,
                                            u16* __restrict__ xb,
                                            u16* __restrict__ wqkvT,
                                            u16* __restrict__ woT) {
    const int b = blockIdx.x;
    const int t = threadIdx.x;
    if (b < 4096) {
        int i = b * 1024 + t * 4;
        float4 v = *reinterpret_cast<const float4*>(&x[i]);
        ushort4 o;
        o.x = f2b(v.x); o.y = f2b(v.y); o.z = f2b(v.z); o.w = f2b(v.w);
        *reinterpret_cast<ushort4*>(&xb[i]) = o;
        return;
    }
    __shared__ float tile[32][33];
    int b2 = b - 4096;
    const float* src; u16* dst; int C, bx, by;
    if (b2 < 4096)      { src = wq; dst = wqkvT;                           C = 2048; bx = b2 & 63; by = b2 >> 6; }
    else if (b2 < 5120) { b2 -= 4096; src = wk; dst = wqkvT + (size_t)2048 * 2048; C = 512; bx = b2 & 15; by = b2 >> 4; }
    else if (b2 < 6144) { b2 -= 5120; src = wv; dst = wqkvT + (size_t)2560 * 2048; C = 512; bx = b2 & 15; by = b2 >> 4; }
    else                { b2 -= 6144; src = wo; dst = woT;                 C = 2048; bx = b2 & 63; by = b2 >> 6; }
    const int c0 = bx * 32, r0 = by * 32;
    const int tr = t >> 5, tc = t & 31;
    #pragma unroll
    for (int i = 0; i < 4; ++i)
        tile[tr + i * 8][tc] = src[(size_t)(r0 + tr + i * 8) * C + c0 + tc];
    __syncthreads();
    #pragma unroll
    for (int i = 0; i < 4; ++i)
        dst[(size_t)(c0 + tr + i * 8) * 2048 + r0 + tc] = f2b(tile[tc][tr + i * 8]);
}

// ---------------------------------------------------------------------------
// bf16 MFMA GEMM: BM=BN=128, BK=64, glds swizzled staging, 256 thr (4 waves,
// each 64x64). MODE 0: fp32 C. MODE 1: QKV epilogue with FUSED RMSNorm+RoPE
// for Q/K (each wave's 64-col strip is exactly one head) and transposed V.
// Q additionally scaled by 0.125*log2(e) (scores move to exp2 domain).
// ---------------------------------------------------------------------------
template<int MODE>
__global__ __launch_bounds__(256) void gemm_glds(const u16* __restrict__ A,
                                                 const u16* __restrict__ Bt,
                                                 float* __restrict__ Cf,
                                                 u16* __restrict__ Qb,
                                                 u16* __restrict__ Kb,
                                                 u16* __restrict__ VtG,
                                                 const float* __restrict__ cosb,
                                                 const float* __restrict__ sinb,
                                                 const float* __restrict__ qnw,
                                                 const float* __restrict__ knw,
                                                 int M, int N, int K) {
    __shared__ u16 As[128 * 64];   // 16 chunks
    __shared__ u16 Bs[128 * 64];   // 16 chunks
    const int t = threadIdx.x;
    const int w = t >> 6, lane = t & 63, quad = lane >> 4, l15 = lane & 15;
    const int m0 = blockIdx.y * 128, n0 = blockIdx.x * 128;
    const int wr = (w >> 1) * 64, wc = (w & 1) * 64;
    const int srow = lane & 7, soct = (lane >> 3) * 8;

    f32x4 acc[4][4];
    #pragma unroll
    for (int mt = 0; mt < 4; ++mt)
        #pragma unroll
        for (int nt = 0; nt < 4; ++nt)
            #pragma unroll
            for (int r = 0; r < 4; ++r) acc[mt][nt][r] = 0.0f;

    for (int k0 = 0; k0 < K; k0 += 64) {
        __syncthreads();
        #pragma unroll
        for (int i = 0; i < 4; ++i) {
            int c = w * 4 + i;   // chunks 0..15 (rows c*8..c*8+7)
            gl2lds16(A  + (size_t)(m0 + c * 8 + srow) * K + k0 + soct, As + c * 512);
            gl2lds16(Bt + (size_t)(n0 + c * 8 + srow) * K + k0 + soct, Bs + c * 512);
        }
        __syncthreads();

        #pragma unroll
        for (int ks = 0; ks < 2; ++ks) {
            const int kk0 = ks * 32 + quad * 8;
            bf16x8 a[4], b[4];
            #pragma unroll
            for (int mt = 0; mt < 4; ++mt)
                a[mt] = *reinterpret_cast<const bf16x8*>(&As[lds_off(wr + mt * 16 + l15, kk0)]);
            #pragma unroll
            for (int nt = 0; nt < 4; ++nt)
                b[nt] = *reinterpret_cast<const bf16x8*>(&Bs[lds_off(wc + nt * 16 + l15, kk0)]);
            #pragma unroll
            for (int mt = 0; mt < 4; ++mt)
                #pragma unroll
                for (int nt = 0; nt < 4; ++nt)
                    acc[mt][nt] = __builtin_amdgcn_mfma_f32_16x16x32_bf16(a[mt], b[nt], acc[mt][nt], 0, 0, 0);
        }
    }

    if (MODE == 0) {
        #pragma unroll
        for (int mt = 0; mt < 4; ++mt)
            #pragma unroll
            for (int nt = 0; nt < 4; ++nt) {
                const int rb  = m0 + wr + mt * 16 + quad * 4;
                const int col = n0 + wc + nt * 16 + l15;
                #pragma unroll
                for (int r = 0; r < 4; ++r)
                    Cf[(size_t)(rb + r) * N + col] = acc[mt][nt][r];
            }
        return;
    }

    // ---- MODE 1 epilogue ----
    const int hb = n0 + wc;               // this wave's 64-col block base
    if (hb >= 2560) {                      // V: transposed packed store
        #pragma unroll
        for (int mt = 0; mt < 4; ++mt)
            #pragma unroll
            for (int nt = 0; nt < 4; ++nt) {
                const int rb = m0 + wr + mt * 16 + quad * 4;
                const int d  = hb - 2560 + nt * 16 + l15;
                ushort4 o;
                o.x = f2b(acc[mt][nt][0]); o.y = f2b(acc[mt][nt][1]);
                o.z = f2b(acc[mt][nt][2]); o.w = f2b(acc[mt][nt][3]);
                *reinterpret_cast<ushort4*>(&VtG[(size_t)d * 2048 + rb]) = o;
            }
        return;
    }

    // Q or K head: fused RMSNorm (fp32) + RoPE
    const bool isQ = hb < 2048;
    const float* nw = isQ ? qnw : knw;
    float wv_[4];
    #pragma unroll
    for (int nt = 0; nt < 4; ++nt) wv_[nt] = nw[nt * 16 + l15];

    #pragma unroll
    for (int mt = 0; mt < 4; ++mt) {
        // sum of squares per row r (rows quad*4+r of this 16-row tile)
        float s2[4] = {0.f, 0.f, 0.f, 0.f};
        #pragma unroll
        for (int nt = 0; nt < 4; ++nt)
            #pragma unroll
            for (int r = 0; r < 4; ++r) s2[r] += acc[mt][nt][r] * acc[mt][nt][r];
        #pragma unroll
        for (int off = 1; off < 16; off <<= 1)
            #pragma unroll
            for (int r = 0; r < 4; ++r) s2[r] += __shfl_xor(s2[r], off);

        float vn[4][4];   // [nt][r]
        #pragma unroll
        for (int r = 0; r < 4; ++r) {
            float rin = rsqrtf(s2[r] * (1.0f / 64.0f) + 1e-6f);
            #pragma unroll
            for (int nt = 0; nt < 4; ++nt) vn[nt][r] = acc[mt][nt][r] * rin * wv_[nt];
        }

        #pragma unroll
        for (int r = 0; r < 4; ++r) {
            const int s = m0 + wr + mt * 16 + quad * 4 + r;
            #pragma unroll
            for (int nt = 0; nt < 4; ++nt) {
                const int d = nt * 16 + l15;
                float c  = cosb[s * 64 + d];
                float sn = sinb[s * 64 + d];
                float sgn = (nt < 2) ? -1.0f : 1.0f;     // rotate_half
                float res = vn[nt][r] * c + sgn * vn[nt ^ 2][r] * sn;
                if (isQ) {
                    res *= 0.18033688f;                   // 0.125 * log2(e)
                    Qb[(size_t)s * 2048 + hb + d] = f2b(res);
                } else {
                    Kb[(size_t)s * 512 + hb - 2048 + d] = f2b(res);
                }
            }
        }
    }
}

// ---------------------------------------------------------------------------
// GQA-fused MFMA flash attention. 512 blocks: b -> kvh=b&7, rem=b>>3,
// qt=31-(rem>>1) (heavy first), hpair=rem&1. Wave w: head = kvh*4+hpair*2
// +(w&1), q-rows qbase = qt*64+(w>>1)*32 (32 rows = 2 16-row strips).
// Double-buffered K/V LDS: prefetch tile kt+1 before computing kt.
// Fixed-shift softmax p=exp2(s-24); direct bf16 writeback (no atomics).
// ---------------------------------------------------------------------------
__global__ __launch_bounds__(256) void attn_fused(const u16* __restrict__ Qb,
                                                  const u16* __restrict__ Kb,
                                                  const u16* __restrict__ VtG,
                                                  u16* __restrict__ attnb) {
    __shared__ u16 Ks[2][4096];   // [buf][kv 64][d 64] swizzled
    __shared__ u16 Vt[2][4096];   // [buf][d 64][kv 64] swizzled

    const int b    = blockIdx.x;
    const int kvh  = b & 7;
    const int rem  = b >> 3;
    const int qt   = 31 - (rem >> 1);
    const int q0   = qt * 64;
    const int t    = threadIdx.x;
    const int w    = t >> 6, lane = t & 63, quad = lane >> 4, l15 = lane & 15;
    const int h    = kvh * 4 + (rem & 1) * 2 + (w & 1);
    const int qbase = q0 + (w >> 1) * 32;
    const int srow = lane & 7, soct = (lane >> 3) * 8;

    // Q B-frags (already exp2-scaled): [qt16][ks]
    bf16x8 qB[2][2];
    #pragma unroll
    for (int q16 = 0; q16 < 2; ++q16) {
        const u16* qr = Qb + (size_t)(qbase + q16 * 16 + l15) * DQ + h * HD;
        qB[q16][0] = *reinterpret_cast<const bf16x8*>(qr + quad * 8);
        qB[q16][1] = *reinterpret_cast<const bf16x8*>(qr + 32 + quad * 8);
    }

    f32x4 o[2][4];
    #pragma unroll
    for (int q16 = 0; q16 < 2; ++q16)
        #pragma unroll
        for (int dt = 0; dt < 4; ++dt)
            #pragma unroll
            for (int r = 0; r < 4; ++r) o[q16][dt][r] = 0.0f;
    float lp[2] = {0.0f, 0.0f};

    // stage tile kt into buffer buf (4 glds16 per wave; 8 chunks K + 8 V total)
    auto stage = [&](int buf, int kt) {
        const int k0 = kt * 64;
        #pragma unroll
        for (int i = 0; i < 2; ++i) {
            int c = w * 2 + i;
            gl2lds16(Kb  + (size_t)(k0 + c * 8 + srow) * DKV + kvh * HD + soct, &Ks[buf][c * 512]);
            gl2lds16(VtG + (size_t)(kvh * HD + c * 8 + srow) * 2048 + k0 + soct, &Vt[buf][c * 512]);
        }
    };

    stage(0, 0);
    for (int kt = 0; kt <= qt; ++kt) {
        const int buf = kt & 1;
        __syncthreads();                    // tile kt ready (prefetched last iter)
        if (kt < qt) stage(buf ^ 1, kt + 1);   // overlap next load with compute
        const u16* ksb = Ks[buf];
        const u16* vtb = Vt[buf];

        // S^T = K . Q^T  (A-frags shared across the two q-strips)
        f32x4 s[2][4];
        #pragma unroll
        for (int q16 = 0; q16 < 2; ++q16)
            #pragma unroll
            for (int kt4 = 0; kt4 < 4; ++kt4)
                #pragma unroll
                for (int r = 0; r < 4; ++r) s[q16][kt4][r] = 0.0f;
        #pragma unroll
        for (int ks = 0; ks < 2; ++ks) {
            const int kk0 = ks * 32 + quad * 8;
            #pragma unroll
            for (int kt4 = 0; kt4 < 4; ++kt4) {
                bf16x8 ka = *reinterpret_cast<const bf16x8*>(&ksb[lds_off(kt4 * 16 + l15, kk0)]);
                s[0][kt4] = __builtin_amdgcn_mfma_f32_16x16x32_bf16(ka, qB[0][ks], s[0][kt4], 0, 0, 0);
                s[1][kt4] = __builtin_amdgcn_mfma_f32_16x16x32_bf16(ka, qB[1][ks], s[1][kt4], 0, 0, 0);
            }
        }

        // mask + exp2 + pack P^T B-frags
        const bool diag = (kt == qt);
        u32 pb[2][4][2];
        #pragma unroll
        for (int q16 = 0; q16 < 2; ++q16) {
            const int qi = (w >> 1) * 32 + q16 * 16 + l15;   // q within 64-tile
            #pragma unroll
            for (int kt4 = 0; kt4 < 4; ++kt4) {
                float p[4];
                #pragma unroll
                for (int r = 0; r < 4; ++r) {
                    float sv = s[q16][kt4][r];
                    if (diag && (kt4 * 16 + quad * 4 + r) > qi) sv = -1e30f;
                    p[r] = exp2f(sv - 24.0f);
                    lp[q16] += p[r];
                }
                pb[q16][kt4][0] = ((u32)f2b(p[1]) << 16) | f2b(p[0]);
                pb[q16][kt4][1] = ((u32)f2b(p[3]) << 16) | f2b(p[2]);
            }
        }

        // O^T += V^T . P^T  (virtual-K: quad's slots j<4 hold kv=kt4*16+quad*4+j)
        #pragma unroll
        for (int kt4 = 0; kt4 < 4; ++kt4) {
            union { bf16x8 v; u32 u[4]; } pu0, pu1;
            pu0.u[0] = pb[0][kt4][0]; pu0.u[1] = pb[0][kt4][1]; pu0.u[2] = 0; pu0.u[3] = 0;
            pu1.u[0] = pb[1][kt4][0]; pu1.u[1] = pb[1][kt4][1]; pu1.u[2] = 0; pu1.u[3] = 0;
            const int kvc = kt4 * 16 + quad * 4;
            #pragma unroll
            for (int dt = 0; dt < 4; ++dt) {
                union { bf16x8 v; u32 u[4]; } va;
                const int row = dt * 16 + l15;
                uint2 vv = *reinterpret_cast<const uint2*>(
                    &vtb[(row >> 3) * 512 + (kvc >> 3) * 64 + (row & 7) * 8 + (kvc & 7)]);
                va.u[0] = vv.x; va.u[1] = vv.y; va.u[2] = 0; va.u[3] = 0;
                o[0][dt] = __builtin_amdgcn_mfma_f32_16x16x32_bf16(va.v, pu0.v, o[0][dt], 0, 0, 0);
                o[1][dt] = __builtin_amdgcn_mfma_f32_16x16x32_bf16(va.v, pu1.v, o[1][dt], 0, 0, 0);
            }
        }
    }

    // normalize + writeback (O^T: d = dt*16+quad*4+r, q = qbase+q16*16+l15)
    #pragma unroll
    for (int q16 = 0; q16 < 2; ++q16) {
        float l = lp[q16];
        l += __shfl_xor(l, 16);
        l += __shfl_xor(l, 32);
        float inv = 1.0f / l;
        #pragma unroll
        for (int dt = 0; dt < 4; ++dt) {
            ushort4 ov;
            ov.x = f2b(o[q16][dt][0] * inv);
            ov.y = f2b(o[q16][dt][1] * inv);
            ov.z = f2b(o[q16][dt][2] * inv);
            ov.w = f2b(o[q16][dt][3] * inv);
            *reinterpret_cast<ushort4*>(attnb + (size_t)(qbase + q16 * 16 + l15) * DQ +
                                        h * HD + dt * 16 + quad * 4) = ov;
        }
    }
}

// ---------------------------------------------------------------------------
extern "C" void kernel_launch(void* const* d_in, const int* in_sizes, int n_in,
                              void* d_out, int out_size, void* d_ws, size_t ws_size,
                              hipStream_t stream) {
    const float* x    = (const float*)d_in[0];
    const float* cosb = (const float*)d_in[1];
    const float* sinb = (const float*)d_in[2];
    const float* wq   = (const float*)d_in[3];
    const float* wk   = (const float*)d_in[4];
    const float* wv   = (const float*)d_in[5];
    const float* wo   = (const float*)d_in[6];
    const float* qnw  = (const float*)d_in[7];
    const float* knw  = (const float*)d_in[8];
    float* out = (float*)d_out;

    char* ws = (char*)d_ws;
    const size_t MB = 1024 * 1024;
    u16* xb    = (u16*)(ws + 0);          // 8 MB
    u16* wqkvT = (u16*)(ws + 8  * MB);    // 12 MB: [wq^T; wk^T; wv^T] [3072][2048]
    u16* woT   = (u16*)(ws + 20 * MB);    // 8 MB
    u16* Qb    = (u16*)(ws + 28 * MB);    // 8 MB
    u16* Kb    = (u16*)(ws + 36 * MB);    // 2 MB
    u16* VtG   = (u16*)(ws + 38 * MB);    // 2 MB  [512][2048]
    u16* attnb = (u16*)(ws + 40 * MB);    // 8 MB

    // 1) prep: cast x + weight transposes
    prep<<<14336, 256, 0, stream>>>(x, wq, wk, wv, wo, xb, wqkvT, woT);

    // 2) fused QKV projection w/ RMSNorm+RoPE epilogue (V transposed)
    gemm_glds<1><<<dim3(3072 / 128, SEQLEN / 128), 256, 0, stream>>>(
        xb, wqkvT, nullptr, Qb, Kb, VtG, cosb, sinb, qnw, knw, SEQLEN, 3072, DIN);

    // 3) GQA-fused causal flash attention
    attn_fused<<<512, 256, 0, stream>>>(Qb, Kb, VtG, attnb);

    // 4) output projection
    gemm_glds<0><<<dim3(DIN / 128, SEQLEN / 128), 256, 0, stream>>>(
        attnb, woT, out, nullptr, nullptr, nullptr, nullptr, nullptr, nullptr, nullptr,
        SEQLEN, DIN, DQ);
}

// Round 7
// 297.470 us; speedup vs baseline: 1.3212x; 1.0370x over previous
//
#include <hip/hip_runtime.h>
#include <math.h>

#define SEQLEN 2048
#define DIN 2048
#define NH 32
#define NKV 8
#define HD 64
#define DQ (NH*HD)    // 2048
#define DKV (NKV*HD)  // 512

using u16 = unsigned short;
using u32 = unsigned int;
using bf16x8 = __attribute__((ext_vector_type(8))) __bf16;
using f32x4  = __attribute__((ext_vector_type(4))) float;

__device__ __forceinline__ u16 f2b(float f) {
    union { float f; u32 u; } x; x.f = f;
    u32 u = x.u;
    u32 r = (u + 0x7fffu + ((u >> 16) & 1u)) >> 16;   // RNE
    return (u16)r;
}
__device__ __forceinline__ u32 fbits(float f) {
    union { float f; u32 u; } x; x.f = f; return x.u;
}

// async global->LDS, 16B/lane; lds base wave-uniform, lane writes at lane*16B.
__device__ __forceinline__ void gl2lds16(const u16* g, u16* l) {
    __builtin_amdgcn_global_load_lds(
        (const __attribute__((address_space(1))) void*)g,
        (__attribute__((address_space(3))) void*)l,
        16, 0, 0);
}

// Swizzled chunk staging: chunk = 8 rows x 64 k (u16), 1 KB.
// Loading lane -> (row = lane&7, k-octet = lane>>3). Elem (row,kk) at
// chunk*512 + (kk>>3)*64 + (row&7)*8 + (kk&7). b128 frag reads cover all
// 32 banks (2-way alias only = free).
__device__ __forceinline__ int lds_off(int row, int kk0) {
    return (row >> 3) * 512 + (kk0 >> 3) * 64 + (row & 7) * 8;
}

// ---------------------------------------------------------------------------
// Fused prep: cast x -> bf16; transpose-cast wq/wk/wv (contiguous [3072][2048])
// and wo.
// ---------------------------------------------------------------------------
__global__ __launch_bounds__(256) void prep(const float* __restrict__ x,
                                            const float* __restrict__ wq,
                                            const float* __restrict__ wk,
                                            const float* __restrict__ wv,
                                            const float* __restrict__ wo,
                                            u16* __restrict__ xb,
                                            u16* __restrict__ wqkvT,
                                            u16* __restrict__ woT) {
    const int b = blockIdx.x;
    const int t = threadIdx.x;
    if (b < 4096) {
        int i = b * 1024 + t * 4;
        float4 v = *reinterpret_cast<const float4*>(&x[i]);
        ushort4 o;
        o.x = f2b(v.x); o.y = f2b(v.y); o.z = f2b(v.z); o.w = f2b(v.w);
        *reinterpret_cast<ushort4*>(&xb[i]) = o;
        return;
    }
    __shared__ float tile[32][33];
    int b2 = b - 4096;
    const float* src; u16* dst; int C, bx, by;
    if (b2 < 4096)      { src = wq; dst = wqkvT;                           C = 2048; bx = b2 & 63; by = b2 >> 6; }
    else if (b2 < 5120) { b2 -= 4096; src = wk; dst = wqkvT + (size_t)2048 * 2048; C = 512; bx = b2 & 15; by = b2 >> 4; }
    else if (b2 < 6144) { b2 -= 5120; src = wv; dst = wqkvT + (size_t)2560 * 2048; C = 512; bx = b2 & 15; by = b2 >> 4; }
    else                { b2 -= 6144; src = wo; dst = woT;                 C = 2048; bx = b2 & 63; by = b2 >> 6; }
    const int c0 = bx * 32, r0 = by * 32;
    const int tr = t >> 5, tc = t & 31;
    #pragma unroll
    for (int i = 0; i < 4; ++i)
        tile[tr + i * 8][tc] = src[(size_t)(r0 + tr + i * 8) * C + c0 + tc];
    __syncthreads();
    #pragma unroll
    for (int i = 0; i < 4; ++i)
        dst[(size_t)(c0 + tr + i * 8) * 2048 + r0 + tc] = f2b(tile[tc][tr + i * 8]);
}

// ---------------------------------------------------------------------------
// bf16 MFMA GEMM v2: BM=128, BN=64, BK=64, double-buffered glds prefetch
// (one barrier per K-step; stage(k+1) issues before compute(k)).
// 256 thr / 4 waves; wave w computes rows [w*32, w*32+32) x all 64 cols
// (mt=2 x nt=4 16x16 tiles, 16 MFMAs per BK64 step).
// MODE 0: fp32 C. MODE 1: QKV epilogue (block = one 64-col head):
// fused RMSNorm+RoPE for Q/K, transposed packed store for V.
// ---------------------------------------------------------------------------
template<int MODE>
__global__ __launch_bounds__(256) void gemm_glds(const u16* __restrict__ A,
                                                 const u16* __restrict__ Bt,
                                                 float* __restrict__ Cf,
                                                 u16* __restrict__ Qb,
                                                 u16* __restrict__ Kb,
                                                 u16* __restrict__ VtG,
                                                 const float* __restrict__ cosb,
                                                 const float* __restrict__ sinb,
                                                 const float* __restrict__ qnw,
                                                 const float* __restrict__ knw,
                                                 int M, int N, int K) {
    __shared__ u16 As[2][128 * 64];   // 16 chunks per buf
    __shared__ u16 Bs[2][64 * 64];    //  8 chunks per buf
    const int t = threadIdx.x;
    const int w = t >> 6, lane = t & 63, quad = lane >> 4, l15 = lane & 15;
    const int m0 = blockIdx.y * 128, n0 = blockIdx.x * 64;
    const int wr = w * 32;
    const int srow = lane & 7, soct = (lane >> 3) * 8;

    f32x4 acc[2][4];
    #pragma unroll
    for (int mt = 0; mt < 2; ++mt)
        #pragma unroll
        for (int nt = 0; nt < 4; ++nt)
            #pragma unroll
            for (int r = 0; r < 4; ++r) acc[mt][nt][r] = 0.0f;

    auto stage = [&](int buf, int k0) {
        #pragma unroll
        for (int i = 0; i < 4; ++i) {
            int c = w * 4 + i;   // A chunks 0..15
            gl2lds16(A + (size_t)(m0 + c * 8 + srow) * K + k0 + soct, &As[buf][c * 512]);
        }
        #pragma unroll
        for (int i = 0; i < 2; ++i) {
            int c = w * 2 + i;   // B chunks 0..7
            gl2lds16(Bt + (size_t)(n0 + c * 8 + srow) * K + k0 + soct, &Bs[buf][c * 512]);
        }
    };

    stage(0, 0);
    const int nsteps = K >> 6;
    for (int st = 0; st < nsteps; ++st) {
        const int buf = st & 1;
        __syncthreads();                       // prefetched buf ready
        if (st + 1 < nsteps) stage(buf ^ 1, (st + 1) << 6);
        #pragma unroll
        for (int ks = 0; ks < 2; ++ks) {
            const int kk0 = ks * 32 + quad * 8;
            bf16x8 a[2], b[4];
            #pragma unroll
            for (int mt = 0; mt < 2; ++mt)
                a[mt] = *reinterpret_cast<const bf16x8*>(&As[buf][lds_off(wr + mt * 16 + l15, kk0)]);
            #pragma unroll
            for (int nt = 0; nt < 4; ++nt)
                b[nt] = *reinterpret_cast<const bf16x8*>(&Bs[buf][lds_off(nt * 16 + l15, kk0)]);
            #pragma unroll
            for (int mt = 0; mt < 2; ++mt)
                #pragma unroll
                for (int nt = 0; nt < 4; ++nt)
                    acc[mt][nt] = __builtin_amdgcn_mfma_f32_16x16x32_bf16(a[mt], b[nt], acc[mt][nt], 0, 0, 0);
        }
    }

    if (MODE == 0) {
        #pragma unroll
        for (int mt = 0; mt < 2; ++mt)
            #pragma unroll
            for (int nt = 0; nt < 4; ++nt) {
                const int rb  = m0 + wr + mt * 16 + quad * 4;
                const int col = n0 + nt * 16 + l15;
                #pragma unroll
                for (int r = 0; r < 4; ++r)
                    Cf[(size_t)(rb + r) * N + col] = acc[mt][nt][r];
            }
        return;
    }

    // ---- MODE 1 epilogue: this block is one 64-col head ----
    const int hb = n0;
    if (hb >= 2560) {                      // V: transposed packed store
        #pragma unroll
        for (int mt = 0; mt < 2; ++mt)
            #pragma unroll
            for (int nt = 0; nt < 4; ++nt) {
                const int rb = m0 + wr + mt * 16 + quad * 4;
                const int d  = hb - 2560 + nt * 16 + l15;
                ushort4 o;
                o.x = f2b(acc[mt][nt][0]); o.y = f2b(acc[mt][nt][1]);
                o.z = f2b(acc[mt][nt][2]); o.w = f2b(acc[mt][nt][3]);
                *reinterpret_cast<ushort4*>(&VtG[(size_t)d * 2048 + rb]) = o;
            }
        return;
    }

    const bool isQ = hb < 2048;
    const float* nw = isQ ? qnw : knw;
    float wv_[4];
    #pragma unroll
    for (int nt = 0; nt < 4; ++nt) wv_[nt] = nw[nt * 16 + l15];

    #pragma unroll
    for (int mt = 0; mt < 2; ++mt) {
        float s2[4] = {0.f, 0.f, 0.f, 0.f};
        #pragma unroll
        for (int nt = 0; nt < 4; ++nt)
            #pragma unroll
            for (int r = 0; r < 4; ++r) s2[r] += acc[mt][nt][r] * acc[mt][nt][r];
        #pragma unroll
        for (int off = 1; off < 16; off <<= 1)
            #pragma unroll
            for (int r = 0; r < 4; ++r) s2[r] += __shfl_xor(s2[r], off);

        float vn[4][4];
        #pragma unroll
        for (int r = 0; r < 4; ++r) {
            float rin = rsqrtf(s2[r] * (1.0f / 64.0f) + 1e-6f);
            #pragma unroll
            for (int nt = 0; nt < 4; ++nt) vn[nt][r] = acc[mt][nt][r] * rin * wv_[nt];
        }

        #pragma unroll
        for (int r = 0; r < 4; ++r) {
            const int s = m0 + wr + mt * 16 + quad * 4 + r;
            #pragma unroll
            for (int nt = 0; nt < 4; ++nt) {
                const int d = nt * 16 + l15;
                float c  = cosb[s * 64 + d];
                float sn = sinb[s * 64 + d];
                float sgn = (nt < 2) ? -1.0f : 1.0f;     // rotate_half
                float res = vn[nt][r] * c + sgn * vn[nt ^ 2][r] * sn;
                if (isQ) {
                    res *= 0.18033688f;                   // 0.125 * log2(e)
                    Qb[(size_t)s * 2048 + hb + d] = f2b(res);
                } else {
                    Kb[(size_t)s * 512 + hb - 2048 + d] = f2b(res);
                }
            }
        }
    }
}

// ---------------------------------------------------------------------------
// GQA-fused MFMA flash attention (r6 structure). 512 blocks: kvh=b&7,
// rem=b>>3, qt=31-(rem>>1), hpair=rem&1. Wave w: head kvh*4+hpair*2+(w&1),
// q-rows qbase..+32. Double-buffered K/V prefetch; fixed-shift softmax
// p=exp2(s-24); P packed to bf16 via v_perm_b32 truncation (1 op/pair).
// ---------------------------------------------------------------------------
__global__ __launch_bounds__(256) void attn_fused(const u16* __restrict__ Qb,
                                                  const u16* __restrict__ Kb,
                                                  const u16* __restrict__ VtG,
                                                  u16* __restrict__ attnb) {
    __shared__ u16 Ks[2][4096];   // [buf][kv 64][d 64] swizzled
    __shared__ u16 Vt[2][4096];   // [buf][d 64][kv 64] swizzled

    const int b    = blockIdx.x;
    const int kvh  = b & 7;
    const int rem  = b >> 3;
    const int qt   = 31 - (rem >> 1);
    const int q0   = qt * 64;
    const int t    = threadIdx.x;
    const int w    = t >> 6, lane = t & 63, quad = lane >> 4, l15 = lane & 15;
    const int h    = kvh * 4 + (rem & 1) * 2 + (w & 1);
    const int qbase = q0 + (w >> 1) * 32;
    const int srow = lane & 7, soct = (lane >> 3) * 8;

    bf16x8 qB[2][2];
    #pragma unroll
    for (int q16 = 0; q16 < 2; ++q16) {
        const u16* qr = Qb + (size_t)(qbase + q16 * 16 + l15) * DQ + h * HD;
        qB[q16][0] = *reinterpret_cast<const bf16x8*>(qr + quad * 8);
        qB[q16][1] = *reinterpret_cast<const bf16x8*>(qr + 32 + quad * 8);
    }

    f32x4 o[2][4];
    #pragma unroll
    for (int q16 = 0; q16 < 2; ++q16)
        #pragma unroll
        for (int dt = 0; dt < 4; ++dt)
            #pragma unroll
            for (int r = 0; r < 4; ++r) o[q16][dt][r] = 0.0f;
    float lp[2] = {0.0f, 0.0f};

    auto stage = [&](int buf, int kt) {
        const int k0 = kt * 64;
        #pragma unroll
        for (int i = 0; i < 2; ++i) {
            int c = w * 2 + i;
            gl2lds16(Kb  + (size_t)(k0 + c * 8 + srow) * DKV + kvh * HD + soct, &Ks[buf][c * 512]);
            gl2lds16(VtG + (size_t)(kvh * HD + c * 8 + srow) * 2048 + k0 + soct, &Vt[buf][c * 512]);
        }
    };

    stage(0, 0);
    for (int kt = 0; kt <= qt; ++kt) {
        const int buf = kt & 1;
        __syncthreads();
        if (kt < qt) stage(buf ^ 1, kt + 1);
        const u16* ksb = Ks[buf];
        const u16* vtb = Vt[buf];

        // S^T = K . Q^T
        f32x4 s[2][4];
        #pragma unroll
        for (int q16 = 0; q16 < 2; ++q16)
            #pragma unroll
            for (int kt4 = 0; kt4 < 4; ++kt4)
                #pragma unroll
                for (int r = 0; r < 4; ++r) s[q16][kt4][r] = 0.0f;
        #pragma unroll
        for (int ks = 0; ks < 2; ++ks) {
            const int kk0 = ks * 32 + quad * 8;
            #pragma unroll
            for (int kt4 = 0; kt4 < 4; ++kt4) {
                bf16x8 ka = *reinterpret_cast<const bf16x8*>(&ksb[lds_off(kt4 * 16 + l15, kk0)]);
                s[0][kt4] = __builtin_amdgcn_mfma_f32_16x16x32_bf16(ka, qB[0][ks], s[0][kt4], 0, 0, 0);
                s[1][kt4] = __builtin_amdgcn_mfma_f32_16x16x32_bf16(ka, qB[1][ks], s[1][kt4], 0, 0, 0);
            }
        }

        // mask + exp2 + truncation-pack P^T B-frags (v_perm_b32)
        const bool diag = (kt == qt);
        u32 pb[2][4][2];
        #pragma unroll
        for (int q16 = 0; q16 < 2; ++q16) {
            const int qi = (w >> 1) * 32 + q16 * 16 + l15;
            #pragma unroll
            for (int kt4 = 0; kt4 < 4; ++kt4) {
                float p[4];
                #pragma unroll
                for (int r = 0; r < 4; ++r) {
                    float sv = s[q16][kt4][r];
                    if (diag && (kt4 * 16 + quad * 4 + r) > qi) sv = -1e30f;
                    p[r] = exp2f(sv - 24.0f);
                    lp[q16] += p[r];
                }
                pb[q16][kt4][0] = __builtin_amdgcn_perm(fbits(p[1]), fbits(p[0]), 0x07060302u);
                pb[q16][kt4][1] = __builtin_amdgcn_perm(fbits(p[3]), fbits(p[2]), 0x07060302u);
            }
        }

        // O^T += V^T . P^T  (virtual-K zero padding)
        #pragma unroll
        for (int kt4 = 0; kt4 < 4; ++kt4) {
            union { bf16x8 v; u32 u[4]; } pu0, pu1;
            pu0.u[0] = pb[0][kt4][0]; pu0.u[1] = pb[0][kt4][1]; pu0.u[2] = 0; pu0.u[3] = 0;
            pu1.u[0] = pb[1][kt4][0]; pu1.u[1] = pb[1][kt4][1]; pu1.u[2] = 0; pu1.u[3] = 0;
            const int kvc = kt4 * 16 + quad * 4;
            #pragma unroll
            for (int dt = 0; dt < 4; ++dt) {
                union { bf16x8 v; u32 u[4]; } va;
                const int row = dt * 16 + l15;
                uint2 vv = *reinterpret_cast<const uint2*>(
                    &vtb[(row >> 3) * 512 + (kvc >> 3) * 64 + (row & 7) * 8 + (kvc & 7)]);
                va.u[0] = vv.x; va.u[1] = vv.y; va.u[2] = 0; va.u[3] = 0;
                o[0][dt] = __builtin_amdgcn_mfma_f32_16x16x32_bf16(va.v, pu0.v, o[0][dt], 0, 0, 0);
                o[1][dt] = __builtin_amdgcn_mfma_f32_16x16x32_bf16(va.v, pu1.v, o[1][dt], 0, 0, 0);
            }
        }
    }

    #pragma unroll
    for (int q16 = 0; q16 < 2; ++q16) {
        float l = lp[q16];
        l += __shfl_xor(l, 16);
        l += __shfl_xor(l, 32);
        float inv = 1.0f / l;
        #pragma unroll
        for (int dt = 0; dt < 4; ++dt) {
            ushort4 ov;
            ov.x = f2b(o[q16][dt][0] * inv);
            ov.y = f2b(o[q16][dt][1] * inv);
            ov.z = f2b(o[q16][dt][2] * inv);
            ov.w = f2b(o[q16][dt][3] * inv);
            *reinterpret_cast<ushort4*>(attnb + (size_t)(qbase + q16 * 16 + l15) * DQ +
                                        h * HD + dt * 16 + quad * 4) = ov;
        }
    }
}

// ---------------------------------------------------------------------------
extern "C" void kernel_launch(void* const* d_in, const int* in_sizes, int n_in,
                              void* d_out, int out_size, void* d_ws, size_t ws_size,
                              hipStream_t stream) {
    const float* x    = (const float*)d_in[0];
    const float* cosb = (const float*)d_in[1];
    const float* sinb = (const float*)d_in[2];
    const float* wq   = (const float*)d_in[3];
    const float* wk   = (const float*)d_in[4];
    const float* wv   = (const float*)d_in[5];
    const float* wo   = (const float*)d_in[6];
    const float* qnw  = (const float*)d_in[7];
    const float* knw  = (const float*)d_in[8];
    float* out = (float*)d_out;

    char* ws = (char*)d_ws;
    const size_t MB = 1024 * 1024;
    u16* xb    = (u16*)(ws + 0);          // 8 MB
    u16* wqkvT = (u16*)(ws + 8  * MB);    // 12 MB: [wq^T; wk^T; wv^T] [3072][2048]
    u16* woT   = (u16*)(ws + 20 * MB);    // 8 MB
    u16* Qb    = (u16*)(ws + 28 * MB);    // 8 MB
    u16* Kb    = (u16*)(ws + 36 * MB);    // 2 MB
    u16* VtG   = (u16*)(ws + 38 * MB);    // 2 MB  [512][2048]
    u16* attnb = (u16*)(ws + 40 * MB);    // 8 MB

    // 1) prep: cast x + weight transposes
    prep<<<14336, 256, 0, stream>>>(x, wq, wk, wv, wo, xb, wqkvT, woT);

    // 2) fused QKV projection w/ RMSNorm+RoPE epilogue (V transposed)
    gemm_glds<1><<<dim3(3072 / 64, SEQLEN / 128), 256, 0, stream>>>(
        xb, wqkvT, nullptr, Qb, Kb, VtG, cosb, sinb, qnw, knw, SEQLEN, 3072, DIN);

    // 3) GQA-fused causal flash attention
    attn_fused<<<512, 256, 0, stream>>>(Qb, Kb, VtG, attnb);

    // 4) output projection
    gemm_glds<0><<<dim3(DIN / 64, SEQLEN / 128), 256, 0, stream>>>(
        attnb, woT, out, nullptr, nullptr, nullptr, nullptr, nullptr, nullptr, nullptr,
        SEQLEN, DIN, DQ);
}

// Round 9
// 284.702 us; speedup vs baseline: 1.3804x; 1.0448x over previous
//
#include <hip/hip_runtime.h>
#include <math.h>

#define SEQLEN 2048
#define DIN 2048
#define NH 32
#define NKV 8
#define HD 64
#define DQ (NH*HD)    // 2048
#define DKV (NKV*HD)  // 512

using u16 = unsigned short;
using u32 = unsigned int;
using bf16x8 = __attribute__((ext_vector_type(8))) __bf16;
using f32x4  = __attribute__((ext_vector_type(4))) float;

__device__ __forceinline__ u16 f2b(float f) {
    union { float f; u32 u; } x; x.f = f;
    u32 u = x.u;
    u32 r = (u + 0x7fffu + ((u >> 16) & 1u)) >> 16;   // RNE
    return (u16)r;
}
__device__ __forceinline__ u32 fbits(float f) {
    union { float f; u32 u; } x; x.f = f; return x.u;
}

// async global->LDS, 16B/lane; lds base wave-uniform, lane i writes i*16B.
__device__ __forceinline__ void gl2lds16(const u16* g, u16* l) {
    __builtin_amdgcn_global_load_lds(
        (const __attribute__((address_space(1))) void*)g,
        (__attribute__((address_space(3))) void*)l,
        16, 0, 0);
}

// --- 8-row x 64-k chunks (512 u16) for attention tiles ----------------------
// loading lane -> (row = lane&7, koct = lane>>3); elem (row,kk) at
// chunk*512 + (kk>>3)*64 + (row&7)*8 + (kk&7). Conflict-free b128 frag reads.
__device__ __forceinline__ int lds_off(int row, int kk0) {
    return (row >> 3) * 512 + (kk0 >> 3) * 64 + (row & 7) * 8;
}
// --- 16-row x 32-k chunks (512 u16) for GEMM tiles --------------------------
// loading lane -> (row = lane&15, koct = lane>>4); elem (row,kk) at
// chunk*512 + (kk>>3)*128 + (row&15)*8 + (kk&7).   [r8 bug: stride was 1024]
__device__ __forceinline__ int lds_off32(int row, int kk0) {
    return (row >> 4) * 512 + (kk0 >> 3) * 128 + (row & 15) * 8;
}

// ---------------------------------------------------------------------------
// Fused prep: cast x -> bf16; transpose-cast wq/wk/wv (contiguous [3072][2048])
// and wo.
// ---------------------------------------------------------------------------
__global__ __launch_bounds__(256) void prep(const float* __restrict__ x,
                                            const float* __restrict__ wq,
                                            const float* __restrict__ wk,
                                            const float* __restrict__ wv,
                                            const float* __restrict__ wo,
                                            u16* __restrict__ xb,
                                            u16* __restrict__ wqkvT,
                                            u16* __restrict__ woT) {
    const int b = blockIdx.x;
    const int t = threadIdx.x;
    if (b < 4096) {
        int i = b * 1024 + t * 4;
        float4 v = *reinterpret_cast<const float4*>(&x[i]);
        ushort4 o;
        o.x = f2b(v.x); o.y = f2b(v.y); o.z = f2b(v.z); o.w = f2b(v.w);
        *reinterpret_cast<ushort4*>(&xb[i]) = o;
        return;
    }
    __shared__ float tile[32][33];
    int b2 = b - 4096;
    const float* src; u16* dst; int C, bx, by;
    if (b2 < 4096)      { src = wq; dst = wqkvT;                           C = 2048; bx = b2 & 63; by = b2 >> 6; }
    else if (b2 < 5120) { b2 -= 4096; src = wk; dst = wqkvT + (size_t)2048 * 2048; C = 512; bx = b2 & 15; by = b2 >> 4; }
    else if (b2 < 6144) { b2 -= 5120; src = wv; dst = wqkvT + (size_t)2560 * 2048; C = 512; bx = b2 & 15; by = b2 >> 4; }
    else                { b2 -= 6144; src = wo; dst = woT;                 C = 2048; bx = b2 & 63; by = b2 >> 6; }
    const int c0 = bx * 32, r0 = by * 32;
    const int tr = t >> 5, tc = t & 31;
    #pragma unroll
    for (int i = 0; i < 4; ++i)
        tile[tr + i * 8][tc] = src[(size_t)(r0 + tr + i * 8) * C + c0 + tc];
    __syncthreads();
    #pragma unroll
    for (int i = 0; i < 4; ++i)
        dst[(size_t)(c0 + tr + i * 8) * 2048 + r0 + tc] = f2b(tile[tc][tr + i * 8]);
}

// ---------------------------------------------------------------------------
// bf16 MFMA GEMM v3: BM=BN=128, BK=32, double-buffered glds prefetch (one
// barrier per step). 4 waves, wave = 64x64 (4x4 16-tiles): 8 b128 reads feed
// 16 MFMAs. MODE 0: fp32 C. MODE 1: QKV epilogue -- each wave's 64-col strip
// is one head: fused RMSNorm+RoPE for Q/K; V stored TRANSPOSED with columns
// interleaved within each 64-seq block:
//   pos(kv) = (b4*2 + (kt4>>1))*8 + (kt4&1)*4 + r,  kt4=kv>>4, b4=(kv>>2)&3,
// so attention's PV uses full-K=32 MFMAs with single b128 V reads.
// ---------------------------------------------------------------------------
template<int MODE>
__global__ __launch_bounds__(256) void gemm_glds(const u16* __restrict__ A,
                                                 const u16* __restrict__ Bt,
                                                 float* __restrict__ Cf,
                                                 u16* __restrict__ Qb,
                                                 u16* __restrict__ Kb,
                                                 u16* __restrict__ VtG,
                                                 const float* __restrict__ cosb,
                                                 const float* __restrict__ sinb,
                                                 const float* __restrict__ qnw,
                                                 const float* __restrict__ knw,
                                                 int M, int N, int K) {
    __shared__ u16 As[2][128 * 32];   // 8 chunks (16r x 32k, 512 u16) per buf
    __shared__ u16 Bs[2][128 * 32];
    const int t = threadIdx.x;
    const int w = t >> 6, lane = t & 63, quad = lane >> 4, l15 = lane & 15;
    const int m0 = blockIdx.y * 128, n0 = blockIdx.x * 128;
    const int wr = (w >> 1) * 64, wc = (w & 1) * 64;
    const int srow = lane & 15, skoct = (lane >> 4) * 8;

    f32x4 acc[4][4];
    #pragma unroll
    for (int mt = 0; mt < 4; ++mt)
        #pragma unroll
        for (int nt = 0; nt < 4; ++nt)
            #pragma unroll
            for (int r = 0; r < 4; ++r) acc[mt][nt][r] = 0.0f;

    auto stage = [&](int buf, int k0) {
        #pragma unroll
        for (int i = 0; i < 2; ++i) {
            int c = w * 2 + i;   // chunks 0..7 (16 rows each)
            gl2lds16(A  + (size_t)(m0 + c * 16 + srow) * K + k0 + skoct, &As[buf][c * 512]);
            gl2lds16(Bt + (size_t)(n0 + c * 16 + srow) * K + k0 + skoct, &Bs[buf][c * 512]);
        }
    };

    stage(0, 0);
    const int nsteps = K >> 5;
    for (int st = 0; st < nsteps; ++st) {
        const int buf = st & 1;
        __syncthreads();                          // prefetched buf ready
        if (st + 1 < nsteps) stage(buf ^ 1, (st + 1) << 5);
        const int kk0 = quad * 8;
        bf16x8 a[4], b[4];
        #pragma unroll
        for (int mt = 0; mt < 4; ++mt)
            a[mt] = *reinterpret_cast<const bf16x8*>(&As[buf][lds_off32(wr + mt * 16 + l15, kk0)]);
        #pragma unroll
        for (int nt = 0; nt < 4; ++nt)
            b[nt] = *reinterpret_cast<const bf16x8*>(&Bs[buf][lds_off32(wc + nt * 16 + l15, kk0)]);
        #pragma unroll
        for (int mt = 0; mt < 4; ++mt)
            #pragma unroll
            for (int nt = 0; nt < 4; ++nt)
                acc[mt][nt] = __builtin_amdgcn_mfma_f32_16x16x32_bf16(a[mt], b[nt], acc[mt][nt], 0, 0, 0);
    }

    if (MODE == 0) {
        #pragma unroll
        for (int mt = 0; mt < 4; ++mt)
            #pragma unroll
            for (int nt = 0; nt < 4; ++nt) {
                const int rb  = m0 + wr + mt * 16 + quad * 4;
                const int col = n0 + wc + nt * 16 + l15;
                #pragma unroll
                for (int r = 0; r < 4; ++r)
                    Cf[(size_t)(rb + r) * N + col] = acc[mt][nt][r];
            }
        return;
    }

    // ---- MODE 1 epilogue: wave strip = one head ----
    const int hb = n0 + wc;
    if (hb >= 2560) {                      // V: transposed, interleaved columns
        #pragma unroll
        for (int mt = 0; mt < 4; ++mt) {
            const int rb  = m0 + wr + mt * 16 + quad * 4;   // seq base (4-aligned)
            const int s64 = rb & 63;
            const int a4  = (s64 >> 4) & 3, b4 = (s64 >> 2) & 3;
            const int colp = (rb & ~63) + (b4 * 2 + (a4 >> 1)) * 8 + (a4 & 1) * 4;
            #pragma unroll
            for (int nt = 0; nt < 4; ++nt) {
                const int d = hb - 2560 + nt * 16 + l15;
                ushort4 o;
                o.x = f2b(acc[mt][nt][0]); o.y = f2b(acc[mt][nt][1]);
                o.z = f2b(acc[mt][nt][2]); o.w = f2b(acc[mt][nt][3]);
                *reinterpret_cast<ushort4*>(&VtG[(size_t)d * 2048 + colp]) = o;
            }
        }
        return;
    }

    const bool isQ = hb < 2048;
    const float* nw = isQ ? qnw : knw;
    float wv_[4];
    #pragma unroll
    for (int nt = 0; nt < 4; ++nt) wv_[nt] = nw[nt * 16 + l15];

    #pragma unroll
    for (int mt = 0; mt < 4; ++mt) {
        float s2[4] = {0.f, 0.f, 0.f, 0.f};
        #pragma unroll
        for (int nt = 0; nt < 4; ++nt)
            #pragma unroll
            for (int r = 0; r < 4; ++r) s2[r] += acc[mt][nt][r] * acc[mt][nt][r];
        #pragma unroll
        for (int off = 1; off < 16; off <<= 1)
            #pragma unroll
            for (int r = 0; r < 4; ++r) s2[r] += __shfl_xor(s2[r], off);

        float vn[4][4];
        #pragma unroll
        for (int r = 0; r < 4; ++r) {
            float rin = rsqrtf(s2[r] * (1.0f / 64.0f) + 1e-6f);
            #pragma unroll
            for (int nt = 0; nt < 4; ++nt) vn[nt][r] = acc[mt][nt][r] * rin * wv_[nt];
        }

        #pragma unroll
        for (int r = 0; r < 4; ++r) {
            const int s = m0 + wr + mt * 16 + quad * 4 + r;
            #pragma unroll
            for (int nt = 0; nt < 4; ++nt) {
                const int d = nt * 16 + l15;
                float c  = cosb[s * 64 + d];
                float sn = sinb[s * 64 + d];
                float sgn = (nt < 2) ? -1.0f : 1.0f;     // rotate_half
                float res = vn[nt][r] * c + sgn * vn[nt ^ 2][r] * sn;
                if (isQ) {
                    res *= 0.18033688f;                   // 0.125 * log2(e)
                    Qb[(size_t)s * 2048 + hb + d] = f2b(res);
                } else {
                    Kb[(size_t)s * 512 + hb - 2048 + d] = f2b(res);
                }
            }
        }
    }
}

// ---------------------------------------------------------------------------
// MFMA flash attention v4. Grid 1024: qt = 31-(b>>5) (heavy first),
// kvh=(b&31)>>2, h=kvh*4+(b&3). Block = ONE head x 64 q-rows, wave w owns
// q-strip w*16..w*16+15. Double-buffered K/V prefetch. Fixed-shift softmax
// p=exp2(s-24). PV uses FULL K=32 MFMAs via column-interleaved V.
// ---------------------------------------------------------------------------
__global__ __launch_bounds__(256) void attn_fused(const u16* __restrict__ Qb,
                                                  const u16* __restrict__ Kb,
                                                  const u16* __restrict__ VtG,
                                                  u16* __restrict__ attnb) {
    __shared__ u16 Ks[2][4096];   // [buf][kv 64][d 64] swizzled 8x64 chunks
    __shared__ u16 Vt[2][4096];   // [buf][d 64][kv 64 interleaved] swizzled

    const int b    = blockIdx.x;
    const int qt   = 31 - (b >> 5);
    const int q0   = qt * 64;
    const int kvh  = (b & 31) >> 2;
    const int h    = kvh * 4 + (b & 3);
    const int t    = threadIdx.x;
    const int w    = t >> 6, lane = t & 63, quad = lane >> 4, l15 = lane & 15;
    const int srow = lane & 7, soct = (lane >> 3) * 8;
    const int qrow = q0 + w * 16 + l15;

    // Q B-frags (exp2-scaled)
    const u16* qr = Qb + (size_t)qrow * DQ + h * HD;
    bf16x8 qB[2];
    qB[0] = *reinterpret_cast<const bf16x8*>(qr + quad * 8);
    qB[1] = *reinterpret_cast<const bf16x8*>(qr + 32 + quad * 8);

    f32x4 o[4];
    #pragma unroll
    for (int dt = 0; dt < 4; ++dt)
        #pragma unroll
        for (int r = 0; r < 4; ++r) o[dt][r] = 0.0f;
    float lpart = 0.0f;

    auto stage = [&](int buf, int kt) {
        const int k0 = kt * 64;
        #pragma unroll
        for (int i = 0; i < 2; ++i) {
            int c = w * 2 + i;
            gl2lds16(Kb  + (size_t)(k0 + c * 8 + srow) * DKV + kvh * HD + soct, &Ks[buf][c * 512]);
            gl2lds16(VtG + (size_t)(kvh * HD + c * 8 + srow) * 2048 + k0 + soct, &Vt[buf][c * 512]);
        }
    };

    stage(0, 0);
    for (int kt = 0; kt <= qt; ++kt) {
        const int buf = kt & 1;
        __syncthreads();
        if (kt < qt) stage(buf ^ 1, kt + 1);
        const u16* ksb = Ks[buf];
        const u16* vtb = Vt[buf];

        // S^T = K . Q^T  (16 q x 64 kv per wave)
        f32x4 s[4];
        #pragma unroll
        for (int kt4 = 0; kt4 < 4; ++kt4)
            #pragma unroll
            for (int r = 0; r < 4; ++r) s[kt4][r] = 0.0f;
        #pragma unroll
        for (int ks = 0; ks < 2; ++ks) {
            const int kk0 = ks * 32 + quad * 8;
            #pragma unroll
            for (int kt4 = 0; kt4 < 4; ++kt4) {
                bf16x8 ka = *reinterpret_cast<const bf16x8*>(&ksb[lds_off(kt4 * 16 + l15, kk0)]);
                s[kt4] = __builtin_amdgcn_mfma_f32_16x16x32_bf16(ka, qB[ks], s[kt4], 0, 0, 0);
            }
        }

        if (kt == qt) {   // wave-uniform: only the diagonal tile masks
            const int qi = w * 16 + l15;   // q index within the 64-tile
            #pragma unroll
            for (int kt4 = 0; kt4 < 4; ++kt4)
                #pragma unroll
                for (int r = 0; r < 4; ++r)
                    if ((kt4 * 16 + quad * 4 + r) > qi) s[kt4][r] = -1e30f;
        }

        // exp2 + pack P^T B-frags
        u32 pb[4][2];
        #pragma unroll
        for (int kt4 = 0; kt4 < 4; ++kt4) {
            float p[4];
            #pragma unroll
            for (int r = 0; r < 4; ++r) {
                p[r] = exp2f(s[kt4][r] - 24.0f);
                lpart += p[r];
            }
            pb[kt4][0] = __builtin_amdgcn_perm(fbits(p[1]), fbits(p[0]), 0x07060302u);
            pb[kt4][1] = __builtin_amdgcn_perm(fbits(p[3]), fbits(p[2]), 0x07060302u);
        }

        // O^T += V^T . P^T : 2 pairs x 4 dt, full-K=32 MFMAs
        #pragma unroll
        for (int pair = 0; pair < 2; ++pair) {
            union { bf16x8 v; u32 u[4]; } pu;
            pu.u[0] = pb[pair * 2][0];     pu.u[1] = pb[pair * 2][1];
            pu.u[2] = pb[pair * 2 + 1][0]; pu.u[3] = pb[pair * 2 + 1][1];
            const int kk0 = (quad * 2 + pair) * 8;   // interleaved V column octet
            #pragma unroll
            for (int dt = 0; dt < 4; ++dt) {
                bf16x8 va = *reinterpret_cast<const bf16x8*>(&vtb[lds_off(dt * 16 + l15, kk0)]);
                o[dt] = __builtin_amdgcn_mfma_f32_16x16x32_bf16(va, pu.v, o[dt], 0, 0, 0);
            }
        }
    }

    lpart += __shfl_xor(lpart, 16);
    lpart += __shfl_xor(lpart, 32);
    float inv = 1.0f / lpart;

    #pragma unroll
    for (int dt = 0; dt < 4; ++dt) {
        ushort4 ov;
        ov.x = f2b(o[dt][0] * inv);
        ov.y = f2b(o[dt][1] * inv);
        ov.z = f2b(o[dt][2] * inv);
        ov.w = f2b(o[dt][3] * inv);
        *reinterpret_cast<ushort4*>(attnb + (size_t)qrow * DQ + h * HD + dt * 16 + quad * 4) = ov;
    }
}

// ---------------------------------------------------------------------------
extern "C" void kernel_launch(void* const* d_in, const int* in_sizes, int n_in,
                              void* d_out, int out_size, void* d_ws, size_t ws_size,
                              hipStream_t stream) {
    const float* x    = (const float*)d_in[0];
    const float* cosb = (const float*)d_in[1];
    const float* sinb = (const float*)d_in[2];
    const float* wq   = (const float*)d_in[3];
    const float* wk   = (const float*)d_in[4];
    const float* wv   = (const float*)d_in[5];
    const float* wo   = (const float*)d_in[6];
    const float* qnw  = (const float*)d_in[7];
    const float* knw  = (const float*)d_in[8];
    float* out = (float*)d_out;

    char* ws = (char*)d_ws;
    const size_t MB = 1024 * 1024;
    u16* xb    = (u16*)(ws + 0);          // 8 MB
    u16* wqkvT = (u16*)(ws + 8  * MB);    // 12 MB: [wq^T; wk^T; wv^T] [3072][2048]
    u16* woT   = (u16*)(ws + 20 * MB);    // 8 MB
    u16* Qb    = (u16*)(ws + 28 * MB);    // 8 MB
    u16* Kb    = (u16*)(ws + 36 * MB);    // 2 MB
    u16* VtG   = (u16*)(ws + 38 * MB);    // 2 MB  [512][2048] col-interleaved
    u16* attnb = (u16*)(ws + 40 * MB);    // 8 MB

    // 1) prep: cast x + weight transposes
    prep<<<14336, 256, 0, stream>>>(x, wq, wk, wv, wo, xb, wqkvT, woT);

    // 2) fused QKV projection w/ RMSNorm+RoPE epilogue (V transposed+interleaved)
    gemm_glds<1><<<dim3(3072 / 128, SEQLEN / 128), 256, 0, stream>>>(
        xb, wqkvT, nullptr, Qb, Kb, VtG, cosb, sinb, qnw, knw, SEQLEN, 3072, DIN);

    // 3) GQA causal flash attention v4
    attn_fused<<<1024, 256, 0, stream>>>(Qb, Kb, VtG, attnb);

    // 4) output projection
    gemm_glds<0><<<dim3(DIN / 128, SEQLEN / 128), 256, 0, stream>>>(
        attnb, woT, out, nullptr, nullptr, nullptr, nullptr, nullptr, nullptr, nullptr,
        SEQLEN, DIN, DQ);
}